// Round 1
// baseline (3942.089 us; speedup 1.0000x reference)
//
#include <hip/hip_runtime.h>
#include <math.h>

#pragma clang fp contract(off)

#define BS 8
#define CCH 20
#define IMH 480
#define IMW 640
#define HW (IMH*IMW)
#define VRX 100
#define NZ 88
#define NSEMC 16
#define CROP0 124
#define CROPN 232
#define NROTC 18

// -------------------- pose / theta params --------------------
__global__ void pose_kernel(const float* __restrict__ pose_obs,
                            const float* __restrict__ poses_last,
                            float* __restrict__ outp1, float* __restrict__ outp2,
                            float* __restrict__ posebuf) {
#pragma clang fp contract(off)
  int b = threadIdx.x;
  if (b >= BS) return;
  const float DEGF = (float)57.29577951308232;
  float th = poses_last[b*3+2] / DEGF;
  float sn = sinf(th), cs = cosf(th);
  float ny = poses_last[b*3+1] + pose_obs[b*3+0]*sn + pose_obs[b*3+1]*cs;
  float nx = poses_last[b*3+0] + pose_obs[b*3+0]*cs - pose_obs[b*3+1]*sn;
  float nt = poses_last[b*3+2] + pose_obs[b*3+2]*DEGF;
  nt = fmodf(nt - 180.0f, 360.0f) + 180.0f;
  nt = fmodf(nt + 180.0f, 360.0f) - 180.0f;
  outp1[b*3+0] = nx; outp1[b*3+1] = ny; outp1[b*3+2] = nt;
  outp2[b*3+0] = nx; outp2[b*3+1] = ny; outp2[b*3+2] = nt;
  float t = (90.0f - nt) * (float)M_PI / 180.0f;
  float* pb = posebuf + b*8;
  pb[0] = cosf(t);
  pb[1] = sinf(t);
  pb[2] = -((nx*100.0f/5.0f - 240.0f)/240.0f);   // stx
  pb[3] = -((ny*100.0f/5.0f - 240.0f)/240.0f);   // sty
}

// -------------------- bottom-row depth mask --------------------
__global__ void mask_kernel(const float* __restrict__ obs, float* __restrict__ posebuf,
                            float MINVF) {
#pragma clang fp contract(off)
  int b = blockIdx.x;
  int t = threadIdx.x;
  const float* row = obs + (size_t)b*CCH*HW + 3*(size_t)HW + 479*IMW;
  int cnt = 0;
  for (int col = t; col < IMW; col += 256) {
    float d = row[col];
    float re = (d < 3000.0f) ? d : MINVF;
    float v = re - MINVF;
    v = v - 60.0f;
    if (v > 0.0f) cnt++;
  }
  __shared__ int sh[256];
  sh[t] = cnt;
  __syncthreads();
  for (int s = 128; s > 0; s >>= 1) {
    if (t < s) sh[t] += sh[t + s];
    __syncthreads();
  }
  if (t == 0) posebuf[b*8+4] = (sh[0] > 160) ? 1.0f : 0.0f;
}

// -------------------- one corner's scatter --------------------
__global__ void scatter_kernel(const float* __restrict__ obs,
                               const float* __restrict__ agent_h,
                               float* __restrict__ S0, float* __restrict__ Ssem,
                               float FOCALF, int ix, int iy, int iz) {
#pragma clang fp contract(off)
  int tid = blockIdx.x*256 + threadIdx.x;
  if (tid >= BS*HW) return;
  int b = tid / HW;
  int pix = tid - b*HW;
  int r = pix / IMW;
  int col = pix - r*IMW;
  float Yd = obs[(size_t)b*CCH*HW + 3*(size_t)HW + pix];
  float ah100 = agent_h[b] * 100.0f;
  // replicate the reference f32 expression order exactly (no contraction)
  float X = ((float)col - 319.5f) * Yd / FOCALF;
  X = X + 250.0f;
  float Z = ((float)(479 - r) - 239.5f) * Yd / FOCALF;
  Z = Z + ah100;
  float Xc = (X/5.0f - 50.0f)/100.0f*2.0f;
  float Yc = (Yd/5.0f - 50.0f)/100.0f*2.0f;
  float Zc = (Z/5.0f - 28.0f)/88.0f*2.0f;
  float pos0 = Xc*50.0f + 50.0f;
  float pos1 = Yc*50.0f + 50.0f;
  float pos2 = Zc*44.0f + 44.0f;
  float p0 = floorf(pos0) + (float)ix;
  float p1 = floorf(pos1) + (float)iy;
  float p2 = floorf(pos2) + (float)iz;
  if (!(p0 > 0.0f && p0 < 100.0f && p1 > 0.0f && p1 < 100.0f &&
        p2 > 0.0f && p2 < 88.0f))
    return;
  float wx = 1.0f - fabsf(pos0 - p0);
  float wy = 1.0f - fabsf(pos1 - p1);
  float wz = 1.0f - fabsf(pos2 - p2);
  float w = wx*wy; w = w*wz;
  if (w == 0.0f) return;
  int xi = (int)p0, yi = (int)p1, zi = (int)p2;
  // S0 layout [b][z][y][x] for coalesced fold
  atomicAdd(&S0[((size_t)(b*NZ + zi)*VRX + yi)*VRX + xi], w);
  if (zi >= 23 && zi < 33) {
    const float* sp = obs + (size_t)b*CCH*HW + 4*(size_t)HW + pix;
    // Ssem layout [b][ch][zrel][y][x]
    float* dp = Ssem + ((size_t)(b*(NSEMC*10)) + (zi-23))*10000 + yi*VRX + xi;
    for (int ch = 0; ch < NSEMC; ch++) {
      float v = sp[(size_t)ch*HW];
      atomicAdd(dp + (size_t)ch*100000, v*w);
    }
  }
}

// -------------------- round + project + clear --------------------
__global__ void fold_kernel(float* __restrict__ S0, float* __restrict__ Ssem,
                            float* __restrict__ ahp0, float* __restrict__ all0,
                            float* __restrict__ around0, float* __restrict__ mid0,
                            float* __restrict__ ahp_sem) {
  int tid = blockIdx.x*256 + threadIdx.x;
  if (tid < 80000) {
    int b = tid / 10000;
    int yx = tid - b*10000;
    float* base = S0 + (size_t)b*NZ*10000 + yx;
    float aall = 0.f, aahp = 0.f, aar = 0.f, amid = 0.f;
    for (int z = 0; z < NZ; z++) {
      float v = base[(size_t)z*10000];
      if (v != 0.0f) {
        base[(size_t)z*10000] = 0.0f;
        float rv = rintf(v);                 // round-half-even == jnp.round
        aall += rv;
        if (z < 23) { aar += rv; if (z >= 9) amid += rv; }
        else if (z < 33) { aahp += rv; }
      }
    }
    all0[tid] += aall; ahp0[tid] += aahp; around0[tid] += aar; mid0[tid] += amid;
  } else if (tid < 80000 + 1280000) {
    int i = tid - 80000;
    int bc = i / 10000;
    int yx = i - bc*10000;
    float* base = Ssem + (size_t)bc*100000 + yx;
    float s = 0.f;
    for (int z = 0; z < 10; z++) {
      float v = base[(size_t)z*10000];
      if (v != 0.0f) { base[(size_t)z*10000] = 0.0f; s += rintf(v); }
    }
    ahp_sem[i] += s;
  }
}

// -------------------- under_floor / clips --------------------
__global__ void finalize_kernel(const float* __restrict__ ahp0, const float* __restrict__ all0,
                                const float* __restrict__ around0, const float* __restrict__ mid0,
                                float* __restrict__ ahp_sem, float* __restrict__ fpexp,
                                const float* __restrict__ posebuf,
                                float* __restrict__ out0) {
#pragma clang fp contract(off)
  int tid = blockIdx.x*256 + threadIdx.x;
  if (tid < 80000) {
    int b = tid / 10000;
    int yx = tid - b*10000;
    int y = yx / 100, x = yx - y*100;
    float u = (mid0[tid] == 0.0f) ? around0[tid] : 0.0f;
    if (y == 28 && x >= 47 && x < 53) {
      if (posebuf[b*8+4] != 0.0f) u = 1.0f;
    }
    float fm = ahp0[tid] + u;
    out0[tid] = fminf(fmaxf(fm, 0.0f), 1.0f);
    fpexp[tid] = fminf(fmaxf(all0[tid], 0.0f), 1.0f);
  } else if (tid < 80000 + 1280000) {
    int i = tid - 80000;
    float v = ahp_sem[i] / 5.0f;
    ahp_sem[i] = fminf(fmaxf(v, 0.0f), 1.0f);
  }
}

// -------------------- rotation resample (cropped support) --------------------
__device__ __forceinline__ float fetch_av(const float* __restrict__ out0,
                                          const float* __restrict__ fpexp,
                                          const float* __restrict__ ahp_sem,
                                          int b, int cidx, float xf, float yf) {
  if (!(xf >= 0.0f && xf <= 479.0f && yf >= 0.0f && yf <= 479.0f)) return 0.0f;
  int xi = (int)xf, yi = (int)yf;
  int wx = xi - 190, wy = yi - 240;
  if (wx < 0 || wx >= 100 || wy < 0 || wy >= 100) return 0.0f;
  int o = b*10000 + wy*100 + wx;
  if (cidx == 0) return out0[o];
  if (cidx == 1) return fpexp[o];
  return ahp_sem[(size_t)(b*NSEMC + (cidx-2))*10000 + wy*100 + wx];
}

__global__ void rotate_kernel(const float* __restrict__ out0, const float* __restrict__ fpexp,
                              const float* __restrict__ ahp_sem,
                              const float* __restrict__ posebuf,
                              float* __restrict__ rot) {
#pragma clang fp contract(off)
  int tid = blockIdx.x*256 + threadIdx.x;
  if (tid >= BS*NROTC*CROPN*CROPN) return;
  int cj = tid % CROPN;
  int t1 = tid / CROPN;
  int ci = t1 % CROPN;
  int t2 = t1 / CROPN;
  int cidx = t2 % NROTC;
  int b = t2 / NROTC;
  int i = ci + CROP0, j = cj + CROP0;
  float X = (2.0f*(float)j + 1.0f)/480.0f - 1.0f;
  float Y = (2.0f*(float)i + 1.0f)/480.0f - 1.0f;
  const float* pb = posebuf + b*8;
  float gx = pb[0]*X - pb[1]*Y;
  float gy = pb[1]*X + pb[0]*Y;
  float x = (gx + 1.0f)*0.5f*479.0f;
  float y = (gy + 1.0f)*0.5f*479.0f;
  float x0 = floorf(x), y0 = floorf(y);
  float wx1 = x - x0, wx0 = 1.0f - wx1;
  float wy1 = y - y0, wy0 = 1.0f - wy1;
  float v00 = fetch_av(out0,fpexp,ahp_sem,b,cidx,x0,       y0);
  float v10 = fetch_av(out0,fpexp,ahp_sem,b,cidx,x0+1.0f,  y0);
  float v01 = fetch_av(out0,fpexp,ahp_sem,b,cidx,x0,       y0+1.0f);
  float v11 = fetch_av(out0,fpexp,ahp_sem,b,cidx,x0+1.0f,  y0+1.0f);
  float val = v00*(wx0*wy0) + v10*(wx1*wy0) + v01*(wx0*wy1) + v11*(wx1*wy1);
  rot[tid] = val;
}

// -------------------- translate + max + output --------------------
__device__ __forceinline__ float fetch_rot(const float* __restrict__ rot,
                                           int b, int cidx, float xf, float yf) {
  if (!(xf >= 0.0f && xf <= 479.0f && yf >= 0.0f && yf <= 479.0f)) return 0.0f;
  int xi = (int)xf, yi = (int)yf;
  int rx = xi - CROP0, ry = yi - CROP0;
  if (rx < 0 || rx >= CROPN || ry < 0 || ry >= CROPN) return 0.0f;
  return rot[((size_t)(b*NROTC + cidx)*CROPN + ry)*CROPN + rx];
}

__global__ void translate_kernel(const float* __restrict__ maps_last,
                                 const float* __restrict__ rot,
                                 const float* __restrict__ posebuf,
                                 float* __restrict__ out1) {
#pragma clang fp contract(off)
  size_t tid = (size_t)blockIdx.x*256 + threadIdx.x;
  if (tid >= (size_t)BS*CCH*480*480) return;
  int j = (int)(tid % 480);
  size_t t1 = tid / 480;
  int i = (int)(t1 % 480);
  size_t t2 = t1 / 480;
  int c = (int)(t2 % CCH);
  int b = (int)(t2 / CCH);
  float ml = maps_last[tid];
  if (c == 2 || c == 3) { out1[tid] = ml; return; }
  int cidx = (c < 2) ? c : c - 2;
  const float* pb = posebuf + b*8;
  float X = (2.0f*(float)j + 1.0f)/480.0f - 1.0f;
  float Y = (2.0f*(float)i + 1.0f)/480.0f - 1.0f;
  float gx = X + pb[2];
  float gy = Y + pb[3];
  float x = (gx + 1.0f)*0.5f*479.0f;
  float y = (gy + 1.0f)*0.5f*479.0f;
  float x0 = floorf(x), y0 = floorf(y);
  float wx1 = x - x0, wx0 = 1.0f - wx1;
  float wy1 = y - y0, wy0 = 1.0f - wy1;
  float v00 = fetch_rot(rot,b,cidx,x0,      y0);
  float v10 = fetch_rot(rot,b,cidx,x0+1.0f, y0);
  float v01 = fetch_rot(rot,b,cidx,x0,      y0+1.0f);
  float v11 = fetch_rot(rot,b,cidx,x0+1.0f, y0+1.0f);
  float val = v00*(wx0*wy0) + v10*(wx1*wy0) + v01*(wx0*wy1) + v11*(wx1*wy1);
  out1[tid] = fmaxf(ml, val);
}

extern "C" void kernel_launch(void* const* d_in, const int* in_sizes, int n_in,
                              void* d_out, int out_size, void* d_ws, size_t ws_size,
                              hipStream_t stream) {
  const float* obs        = (const float*)d_in[0];
  const float* pose_obs   = (const float*)d_in[1];
  const float* maps_last  = (const float*)d_in[2];
  const float* poses_last = (const float*)d_in[3];
  const float* agent_h    = (const float*)d_in[4];
  float* out = (float*)d_out;
  float* ws  = (float*)d_ws;

  const size_t WS_NEED = (size_t)64 + 80000ull*5 + 1280000ull + 7040000ull + 12800000ull;
  if (ws_size < WS_NEED*sizeof(float)) return;  // refuse to write OOB

  double focal_d = 640.0/2.0/tan(79.0/2.0*M_PI/180.0);
  float FOCALF = (float)focal_d;
  double vfov = atan(480.0/2.0/focal_d);
  float MINVF = (float)((0.88*100.0)/tan(vfov));

  float* posebuf = ws;                       // 64 floats
  float* ahp0    = ws + 64;                  // 80000
  float* all0    = ahp0 + 80000;             // 80000
  float* around0 = all0 + 80000;             // 80000
  float* mid0    = around0 + 80000;          // 80000
  float* fpexp   = mid0 + 80000;             // 80000
  float* ahp_sem = fpexp + 80000;            // 1,280,000
  float* S0      = ahp_sem + 1280000;        // 7,040,000
  float* Ssem    = S0 + 7040000;             // 12,800,000
  float* rot     = S0;                       // reuse scratch (7,750,656 fits)

  float* out0  = out;                        // fp_map_pred (8,1,100,100)
  float* out1  = out + 80000;                // map_pred (8,20,480,480)
  float* outp1 = out1 + (size_t)BS*CCH*480*480;
  float* outp2 = outp1 + 24;

  hipMemsetAsync(ahp0, 0,
                 ((size_t)80000*5 + 1280000ull + 7040000ull + 12800000ull)*sizeof(float),
                 stream);
  pose_kernel<<<1, 64, 0, stream>>>(pose_obs, poses_last, outp1, outp2, posebuf);
  mask_kernel<<<BS, 256, 0, stream>>>(obs, posebuf, MINVF);
  for (int k = 0; k < 8; k++) {
    scatter_kernel<<<9600, 256, 0, stream>>>(obs, agent_h, S0, Ssem, FOCALF,
                                             (k>>2)&1, (k>>1)&1, k&1);
    fold_kernel<<<5313, 256, 0, stream>>>(S0, Ssem, ahp0, all0, around0, mid0, ahp_sem);
  }
  finalize_kernel<<<5313, 256, 0, stream>>>(ahp0, all0, around0, mid0, ahp_sem,
                                            fpexp, posebuf, out0);
  rotate_kernel<<<30276, 256, 0, stream>>>(out0, fpexp, ahp_sem, posebuf, rot);
  translate_kernel<<<144000, 256, 0, stream>>>(maps_last, rot, posebuf, out1);
}